// Round 5
// baseline (306.592 us; speedup 1.0000x reference)
//
#include <hip/hip_runtime.h>
#include <hip/hip_bf16.h>
#include <stdint.h>

// Problem constants
#define B_BATCH 32
#define M_SEQ   512
#define R_TOT   16384      // B*M
#define D_IN    1024
#define E_DIM   2048       // lmd*d
#define NCAT    384        // 256 (G*NC) + 8 (G) padded to 3*128
#define NVALID  264
#define G_GRP   8
#define NC_CL   32
#define ND_     256

typedef float  f32x4 __attribute__((ext_vector_type(4)));
typedef short  s16x8 __attribute__((ext_vector_type(8)));

__device__ __forceinline__ uint16_t f2bf(float f) {
  uint32_t u = __builtin_bit_cast(uint32_t, f);
  uint32_t r = (u + 0x7fffu + ((u >> 16) & 1u)) >> 16;
  return (uint16_t)r;
}
__device__ __forceinline__ float bf2f(uint16_t u) {
  return __builtin_bit_cast(float, (uint32_t)u << 16);
}

// MFMA via inline asm (verified layouts: A row=lane&15,k=(lane>>4)*8+i ; B col=lane&15,same k ;
// C/D col=lane&15,row=(lane>>4)*4+reg  [learn_hip m89/m91])
__device__ __forceinline__ f32x4 mfma_bf16(s16x8 a, s16x8 b, f32x4 c) {
  asm("v_mfma_f32_16x16x32_bf16 %0, %1, %2, %0" : "+v"(c) : "v"(a), "v"(b));
  return c;
}

typedef __attribute__((address_space(3))) void lds_void_t;
typedef const __attribute__((address_space(1))) void gbl_void_t;
__device__ __forceinline__ void async_load16(const void* g, void* l) {
  __builtin_amdgcn_global_load_lds((gbl_void_t*)g, (lds_void_t*)l, 16, 0, 0);
}

// ---------------- prep kernels ----------------
__global__ void zero_buf(float* __restrict__ p, int n) {
  int i = blockIdx.x * blockDim.x + threadIdx.x;
  if (i < n) p[i] = 0.0f;
}

__global__ void cvt_bf16(const float* __restrict__ src, uint16_t* __restrict__ dst, int n) {
  int i = blockIdx.x * blockDim.x + threadIdx.x;
  if (i < n) dst[i] = f2bf(src[i]);
}

__global__ void build_wcat(const float* __restrict__ W1, const float* __restrict__ W2,
                           uint16_t* __restrict__ wcat) {
  int i = blockIdx.x * blockDim.x + threadIdx.x;  // over 384*2048
  if (i >= NCAT * E_DIM) return;
  int row = i >> 11, col = i & (E_DIM - 1);
  float v = 0.0f;
  if (row < 256) v = W1[i];
  else if (row < NVALID) v = W2[(row - 256) * E_DIM + col];
  wcat[i] = f2bf(v);
}

__global__ void build_bcat(const float* __restrict__ b1, const float* __restrict__ b2,
                           float* __restrict__ bcat) {
  int i = blockIdx.x * blockDim.x + threadIdx.x;
  if (i >= NCAT) return;
  float v = 0.0f;
  if (i < 256) v = b1[i];
  else if (i < NVALID) v = b2[i - 256];
  bcat[i] = v;
}

// ---------------- row L2-normalize -> bf16 ----------------
__global__ __launch_bounds__(256) void normalize_rows(const float* __restrict__ x,
                                                      uint16_t* __restrict__ xn) {
  const int r = blockIdx.x, tid = threadIdx.x;
  const float4* xr = (const float4*)(x + (size_t)r * D_IN);
  float4 v = xr[tid];
  float ss = v.x * v.x + v.y * v.y + v.z * v.z + v.w * v.w;
  #pragma unroll
  for (int m = 32; m; m >>= 1) ss += __shfl_xor(ss, m);
  __shared__ float wsum[4];
  if ((tid & 63) == 0) wsum[tid >> 6] = ss;
  __syncthreads();
  float tot = wsum[0] + wsum[1] + wsum[2] + wsum[3];
  float scale = 1.0f / fmaxf(sqrtf(tot), 1e-12f);
  uint16_t* o = xn + (size_t)r * D_IN + tid * 4;
  o[0] = f2bf(v.x * scale); o[1] = f2bf(v.y * scale);
  o[2] = f2bf(v.z * scale); o[3] = f2bf(v.w * scale);
}

// ---------------- MFMA GEMM: C[M,N] = A[M,K] @ B[N,K]^T + bias ----------------
// 128x128 tile, BK=64, 4 waves (2x2 of 64x64), m97-style linear-LDS global_load_lds staging.
template <typename OutT>
__global__ __launch_bounds__(256, 2) void gemm_bt(
    const uint16_t* __restrict__ A, const uint16_t* __restrict__ B,
    const float* __restrict__ bias, OutT* __restrict__ C, int N, int K) {
  __shared__ __align__(16) uint16_t As[128 * 64];
  __shared__ __align__(16) uint16_t Bs[128 * 64];
  const int tid = threadIdx.x;
  const int w = tid >> 6, lane = tid & 63;
  const int wr = w >> 1, wc = w & 1;
  const int tm = blockIdx.x, tn = blockIdx.y;

  f32x4 acc[4][4] = {};

  const int lrow = lane >> 3;       // 0..7   (row within 8-row staging stripe)
  const int lk = (lane & 7) * 8;    // k chunk: 8 bf16 = 16B
  const size_t a_row0 = (size_t)tm * 128;
  const size_t b_row0 = (size_t)tn * 128;

  for (int k0 = 0; k0 < K; k0 += 64) {
    #pragma unroll
    for (int j = 0; j < 4; ++j) {
      const int c = w * 4 + j;            // 16 stripes of 8 rows
      const int row = c * 8 + lrow;
      async_load16(A + (a_row0 + row) * K + k0 + lk, (void*)(As + c * 512));
      async_load16(B + (b_row0 + row) * K + k0 + lk, (void*)(Bs + c * 512));
    }
    __syncthreads();   // drains vmcnt(0)
    #pragma unroll
    for (int kk = 0; kk < 2; ++kk) {
      const int krow = kk * 32 + (lane >> 4) * 8;
      s16x8 af[4], bfr[4];
      #pragma unroll
      for (int mi = 0; mi < 4; ++mi)
        af[mi] = *(const s16x8*)&As[(wr * 64 + mi * 16 + (lane & 15)) * 64 + krow];
      #pragma unroll
      for (int ni = 0; ni < 4; ++ni)
        bfr[ni] = *(const s16x8*)&Bs[(wc * 64 + ni * 16 + (lane & 15)) * 64 + krow];
      #pragma unroll
      for (int mi = 0; mi < 4; ++mi)
        #pragma unroll
        for (int ni = 0; ni < 4; ++ni)
          acc[mi][ni] = mfma_bf16(af[mi], bfr[ni], acc[mi][ni]);
    }
    __syncthreads();
  }
  asm volatile("s_nop 7\n\ts_nop 7\n\ts_nop 7" ::);  // MFMA->VALU read hazard drain

  const int rbase = wr * 64 + (lane >> 4) * 4;
  const int cbase = wc * 64 + (lane & 15);
  #pragma unroll
  for (int ni = 0; ni < 4; ++ni) {
    const int col = tn * 128 + cbase + ni * 16;
    const float bv = bias[col];
    #pragma unroll
    for (int mi = 0; mi < 4; ++mi) {
      #pragma unroll
      for (int jj = 0; jj < 4; ++jj) {
        const int row = tm * 128 + rbase + mi * 16 + jj;
        float v = acc[mi][ni][jj] + bv;
        if constexpr (sizeof(OutT) == 2) C[(size_t)row * N + col] = (OutT)f2bf(v);
        else                             C[(size_t)row * N + col] = v;
      }
    }
  }
}

// ---------------- fused softmax + partial accumulate ----------------
// Per block: 32 rows (one batch). t1[b,d'] += sum_g a2*xe_g ; S[b,k] += sum_g a2*a1[g,k]
__global__ __launch_bounds__(256) void softmax_accum(
    const float* __restrict__ logits,   // R x 384 (cols 0..255 = a1 logits, 256..263 = a2)
    const uint16_t* __restrict__ xe,    // R x 2048 bf16
    float* __restrict__ t1,             // 32 x 256
    float* __restrict__ sacc) {         // 32 x 32
  const int tid = threadIdx.x;
  const int r0 = blockIdx.x * 32;
  const int b = r0 >> 9;               // 512 rows per batch
  __shared__ float p1s[256];
  __shared__ float a2s[8];
  float t1_local = 0.0f, s_local = 0.0f;

  for (int rr = 0; rr < 32; ++rr) {
    const int r = r0 + rr;
    const float* lrow = logits + (size_t)r * NCAT;
    // softmax over NC=32 within each group (32 contiguous lanes within a wave)
    float lg = lrow[tid];
    float mx = lg;
    #pragma unroll
    for (int m = 16; m; m >>= 1) mx = fmaxf(mx, __shfl_xor(mx, m));
    float e = __expf(lg - mx);
    float sm = e;
    #pragma unroll
    for (int m = 16; m; m >>= 1) sm += __shfl_xor(sm, m);
    p1s[tid] = e / sm;
    if (tid < 8) {   // a2 softmax over 8 groups (lanes 0..7)
      float l2 = lrow[256 + tid];
      float m2 = l2;
      #pragma unroll
      for (int m = 4; m; m >>= 1) m2 = fmaxf(m2, __shfl_xor(m2, m));
      float e2 = __expf(l2 - m2);
      float s2 = e2;
      #pragma unroll
      for (int m = 4; m; m >>= 1) s2 += __shfl_xor(s2, m);
      a2s[tid] = e2 / s2;
    }
    __syncthreads();
    const uint16_t* xr = xe + (size_t)r * E_DIM;
    float a = 0.0f;
    #pragma unroll
    for (int g = 0; g < 8; ++g) a += a2s[g] * bf2f(xr[g * 256 + tid]);
    t1_local += a;
    if (tid < 32) {
      float sa = 0.0f;
      #pragma unroll
      for (int g = 0; g < 8; ++g) sa += a2s[g] * p1s[g * 32 + tid];
      s_local += sa;
    }
    __syncthreads();
  }
  atomicAdd(&t1[b * 256 + tid], t1_local);
  if (tid < 32) atomicAdd(&sacc[b * 32 + tid], s_local);
}

// ---------------- finalize: v = (t1 - S@centroid)/m ; out = l2norm(v) ----------------
__global__ __launch_bounds__(256) void finalize(const float* __restrict__ t1,
                                                const float* __restrict__ sacc,
                                                const float* __restrict__ centroid,
                                                float* __restrict__ out) {
  const int b = blockIdx.x, tid = threadIdx.x;
  float cs = 0.0f;
  #pragma unroll
  for (int k = 0; k < 32; ++k) cs += sacc[b * 32 + k] * centroid[k * 256 + tid];
  float v = (t1[b * 256 + tid] - cs) * (1.0f / (float)M_SEQ);
  float ss = v * v;
  #pragma unroll
  for (int m = 32; m; m >>= 1) ss += __shfl_xor(ss, m);
  __shared__ float wsum[4];
  if ((tid & 63) == 0) wsum[tid >> 6] = ss;
  __syncthreads();
  float tot = wsum[0] + wsum[1] + wsum[2] + wsum[3];
  out[b * 256 + tid] = v / fmaxf(sqrtf(tot), 1e-12f);
}

extern "C" void kernel_launch(void* const* d_in, const int* in_sizes, int n_in,
                              void* d_out, int out_size, void* d_ws, size_t ws_size,
                              hipStream_t stream) {
  const float* x        = (const float*)d_in[0];
  // d_in[1] = mask (unused by reference math)
  const float* We       = (const float*)d_in[2];
  const float* be       = (const float*)d_in[3];
  const float* W1       = (const float*)d_in[4];
  const float* b1       = (const float*)d_in[5];
  const float* W2       = (const float*)d_in[6];
  const float* b2       = (const float*)d_in[7];
  const float* centroid = (const float*)d_in[8];
  float* out = (float*)d_out;

  char* ws = (char*)d_ws;
  // workspace layout (bytes), total ~101.5 MB.
  // logits ALIASES xn: safe by stream order (normalize writes xn -> GEMM1 reads xn,
  // writes xe -> GEMM2 reads xe, writes logits -> softmax_accum reads logits+xe).
  uint16_t* xe     = (uint16_t*)(ws + 0);          //  64 MB  R x 2048 bf16
  uint16_t* xn     = (uint16_t*)(ws + 67108864);   //  32 MB  R x 1024 bf16
  float*    logits = (float*)  (ws + 67108864);    //  24 MB  R x 384 f32 (aliases xn)
  uint16_t* webf   = (uint16_t*)(ws + 100663296);  //   4 MB  2048 x 1024 bf16
  uint16_t* wcat   = (uint16_t*)(ws + 104857600);  // 1.5 MB  384 x 2048 bf16
  float*    bcat   = (float*)  (ws + 106430464);   //  1.5 KB 384 f32
  float*    t1     = (float*)  (ws + 106432000);   //  32 KB  32 x 256
  float*    sacc   = (float*)  (ws + 106464768);   //   4 KB  32 x 32

  // prep
  zero_buf  <<<dim3(36),   256, 0, stream>>>(t1, 8192 + 1024);  // t1 + sacc contiguous
  cvt_bf16  <<<dim3(8192), 256, 0, stream>>>(We, webf, E_DIM * D_IN);
  build_wcat<<<dim3(3072), 256, 0, stream>>>(W1, W2, wcat);
  build_bcat<<<dim3(2),    256, 0, stream>>>(b1, b2, bcat);

  // pipeline
  normalize_rows<<<dim3(R_TOT), 256, 0, stream>>>(x, xn);
  gemm_bt<uint16_t><<<dim3(R_TOT / 128, E_DIM / 128), 256, 0, stream>>>(
      xn, webf, be, xe, E_DIM, D_IN);
  gemm_bt<float><<<dim3(R_TOT / 128, NCAT / 128), 256, 0, stream>>>(
      xe, wcat, bcat, logits, NCAT, E_DIM);
  softmax_accum<<<dim3(R_TOT / 32), 256, 0, stream>>>(logits, xe, t1, sacc);
  finalize<<<dim3(B_BATCH), 256, 0, stream>>>(t1, sacc, centroid, out);
}

// Round 6
// 300.947 us; speedup vs baseline: 1.0188x; 1.0188x over previous
//
#include <hip/hip_runtime.h>
#include <hip/hip_bf16.h>
#include <stdint.h>

// Problem constants
#define B_BATCH 32
#define M_SEQ   512
#define R_TOT   16384      // B*M
#define D_IN    1024
#define E_DIM   2048       // lmd*d
#define NCAT    384        // 256 (G*NC) + 8 (G) padded to 3*128
#define NVALID  264

typedef float  f32x4 __attribute__((ext_vector_type(4)));
typedef short  s16x8 __attribute__((ext_vector_type(8)));

__device__ __forceinline__ uint16_t f2bf(float f) {
  uint32_t u = __builtin_bit_cast(uint32_t, f);
  uint32_t r = (u + 0x7fffu + ((u >> 16) & 1u)) >> 16;
  return (uint16_t)r;
}
__device__ __forceinline__ float bf2f(uint16_t u) {
  return __builtin_bit_cast(float, (uint32_t)u << 16);
}

__device__ __forceinline__ f32x4 mfma_bf16(s16x8 a, s16x8 b, f32x4 c) {
  asm("v_mfma_f32_16x16x32_bf16 %0, %1, %2, %0" : "+v"(c) : "v"(a), "v"(b));
  return c;
}

typedef __attribute__((address_space(3))) void lds_void_t;
typedef const __attribute__((address_space(1))) void gbl_void_t;
__device__ __forceinline__ void async_load16(const void* g, void* l) {
  __builtin_amdgcn_global_load_lds((gbl_void_t*)g, (lds_void_t*)l, 16, 0, 0);
}

#define FENCE() __builtin_amdgcn_sched_barrier(0)
#define PH_PRE() do { FENCE(); __builtin_amdgcn_s_barrier(); FENCE(); \
                      asm volatile("s_waitcnt lgkmcnt(0)" ::: "memory"); FENCE(); \
                      __builtin_amdgcn_s_setprio(1); } while (0)
#define PH_POST() do { __builtin_amdgcn_s_setprio(0); FENCE(); \
                       __builtin_amdgcn_s_barrier(); FENCE(); } while (0)
#define PH_POST_VM4() do { __builtin_amdgcn_s_setprio(0); FENCE(); \
                       asm volatile("s_waitcnt vmcnt(4)" ::: "memory"); FENCE(); \
                       __builtin_amdgcn_s_barrier(); FENCE(); } while (0)
#define PH_POST_VM0() do { __builtin_amdgcn_s_setprio(0); FENCE(); \
                       asm volatile("s_waitcnt vmcnt(0)" ::: "memory"); FENCE(); \
                       __builtin_amdgcn_s_barrier(); FENCE(); } while (0)

// ---------------- prep kernels ----------------
__global__ void zero_buf(float* __restrict__ p, int n) {
  int i = blockIdx.x * blockDim.x + threadIdx.x;
  if (i < n) p[i] = 0.0f;
}

__global__ void cvt_bf16(const float* __restrict__ src, uint16_t* __restrict__ dst, int n) {
  int i = blockIdx.x * blockDim.x + threadIdx.x;
  if (i < n) dst[i] = f2bf(src[i]);
}

__global__ void build_wcat(const float* __restrict__ W1, const float* __restrict__ W2,
                           uint16_t* __restrict__ wcat) {
  int i = blockIdx.x * blockDim.x + threadIdx.x;
  if (i >= NCAT * E_DIM) return;
  int row = i >> 11, col = i & (E_DIM - 1);
  float v = 0.0f;
  if (row < 256) v = W1[i];
  else if (row < NVALID) v = W2[(row - 256) * E_DIM + col];
  wcat[i] = f2bf(v);
}

__global__ void build_bcat(const float* __restrict__ b1, const float* __restrict__ b2,
                           float* __restrict__ bcat) {
  int i = blockIdx.x * blockDim.x + threadIdx.x;
  if (i >= NCAT) return;
  float v = 0.0f;
  if (i < 256) v = b1[i];
  else if (i < NVALID) v = b2[i - 256];
  bcat[i] = v;
}

// ---------------- row L2-normalize -> bf16 ----------------
__global__ __launch_bounds__(256) void normalize_rows(const float* __restrict__ x,
                                                      uint16_t* __restrict__ xn) {
  const int r = blockIdx.x, tid = threadIdx.x;
  const float4* xr = (const float4*)(x + (size_t)r * D_IN);
  float4 v = xr[tid];
  float ss = v.x * v.x + v.y * v.y + v.z * v.z + v.w * v.w;
  #pragma unroll
  for (int m = 32; m; m >>= 1) ss += __shfl_xor(ss, m);
  __shared__ float wsum[4];
  if ((tid & 63) == 0) wsum[tid >> 6] = ss;
  __syncthreads();
  float tot = wsum[0] + wsum[1] + wsum[2] + wsum[3];
  float scale = 1.0f / fmaxf(sqrtf(tot), 1e-12f);
  uint16_t* o = xn + (size_t)r * D_IN + tid * 4;
  o[0] = f2bf(v.x * scale); o[1] = f2bf(v.y * scale);
  o[2] = f2bf(v.z * scale); o[3] = f2bf(v.w * scale);
}

// ---------------- 256x256 8-phase MFMA GEMM (T2+T3+T4+T5) ----------------
// C[M,N] = A[M,K] @ B[N,K]^T + bias, bf16 out. 512 thr (8 waves 2Mx4N), BK=64,
// LDS [2 buf][A/B][2 half][128x64] = 128 KB, XOR-chunk swizzle (chunk ^= row&7)
// via pre-swizzled global source + swizzled ds_read. Counted vmcnt(4) per group.
template <int KDIM>
__global__ __launch_bounds__(512, 2) void gemm256(
    const uint16_t* __restrict__ A, const uint16_t* __restrict__ B,
    const float* __restrict__ bias, uint16_t* __restrict__ C, int N) {
  __shared__ uint16_t lds[65536];
  constexpr int NT = KDIM / 64;
  const int tid = threadIdx.x;
  const int w = tid >> 6, lane = tid & 63;
  const int wr = w >> 2, wc = w & 3;
  const int bm = blockIdx.x, bn = blockIdx.y;

  // staging constants: thread -> (row srow, chunk tid&7); source uses chunk^(row&7)
  const int srow = tid >> 3;
  const int scol = (((tid & 7) ^ (srow & 7)) << 3);
  // ds_read constants: row = *16 + (lane&15) -> key = lane&7
  const int l15 = lane & 15, l4 = lane >> 4, lx = lane & 7;
  const int ck0 = ((l4) ^ lx) << 4;        // byte offset of kk=0 16B chunk
  const int ck1 = ((4 + l4) ^ lx) << 4;    // kk=1

  const int arow0 = bm * 256, brow0 = bn * 256;

  auto STAGE = [&](const uint16_t* __restrict__ M, int grow0, int tile,
                   int bufi, int mat, int half) {
    if (tile >= NT) return;
    const uint16_t* src = M + (size_t)(grow0 + half * 128 + srow) * KDIM + tile * 64 + scol;
    uint16_t* dst = lds + ((bufi * 2 + mat) * 2 + half) * 8192 + w * 512;
    async_load16(src, dst);
    async_load16(src + (size_t)64 * KDIM, dst + 4096);
  };
  auto LDA = [&](int bufi, int mi, int ckb) -> s16x8 {
    return *(const s16x8*)((const char*)(lds + ((bufi * 2 + 0) * 2 + wr) * 8192)
                           + (mi * 16 + l15) * 128 + ckb);
  };
  auto LDB = [&](int bufi, int ni, int ckb) -> s16x8 {
    return *(const s16x8*)((const char*)(lds + ((bufi * 2 + 1) * 2 + (wc >> 1)) * 8192)
                           + ((wc & 1) * 64 + ni * 16 + l15) * 128 + ckb);
  };

  f32x4 acc[8][4] = {};
  s16x8 aF[4][2], bF[4][2];

  // prologue: tile0 fully, tile1 B-halves; allow tile1's 4 loads outstanding
  STAGE(A, arow0, 0, 0, 0, 0); STAGE(A, arow0, 0, 0, 0, 1);
  STAGE(B, brow0, 0, 0, 1, 0); STAGE(B, brow0, 0, 0, 1, 1);
  STAGE(B, brow0, 1, 1, 1, 0); STAGE(B, brow0, 1, 1, 1, 1);
  asm volatile("s_waitcnt vmcnt(4)" ::: "memory");
  __builtin_amdgcn_s_barrier(); FENCE();

  for (int i = 0; i < NT / 2; ++i) {
    const bool last = (i == NT / 2 - 1);
    #pragma unroll
    for (int h = 0; h < 2; ++h) {
      const int T = 2 * i + h;
      // ---- g1: read a0-3,b0-1 of buf h; stage (buf h^1).A0 <- tile T+1
      #pragma unroll
      for (int mi = 0; mi < 4; ++mi) { aF[mi][0] = LDA(h, mi, ck0); aF[mi][1] = LDA(h, mi, ck1); }
      #pragma unroll
      for (int ni = 0; ni < 2; ++ni) { bF[ni][0] = LDB(h, ni, ck0); bF[ni][1] = LDB(h, ni, ck1); }
      STAGE(A, arow0, T + 1, h ^ 1, 0, 0);
      PH_PRE();
      #pragma unroll
      for (int mi = 0; mi < 4; ++mi)
        #pragma unroll
        for (int ni = 0; ni < 2; ++ni)
          #pragma unroll
          for (int kk = 0; kk < 2; ++kk)
            acc[mi][ni] = mfma_bf16(aF[mi][kk], bF[ni][kk], acc[mi][ni]);
      PH_POST();
      // ---- g2: read b2-3; stage (buf h^1).A1 <- tile T+1
      #pragma unroll
      for (int ni = 2; ni < 4; ++ni) { bF[ni][0] = LDB(h, ni, ck0); bF[ni][1] = LDB(h, ni, ck1); }
      STAGE(A, arow0, T + 1, h ^ 1, 0, 1);
      PH_PRE();
      #pragma unroll
      for (int mi = 0; mi < 4; ++mi)
        #pragma unroll
        for (int ni = 2; ni < 4; ++ni)
          #pragma unroll
          for (int kk = 0; kk < 2; ++kk)
            acc[mi][ni] = mfma_bf16(aF[mi][kk], bF[ni][kk], acc[mi][ni]);
      PH_POST();
      // ---- g3: read a4-7 (B-halves of buf h now dead); stage (buf h).B0 <- tile T+2
      #pragma unroll
      for (int mi = 0; mi < 4; ++mi) { aF[mi][0] = LDA(h, 4 + mi, ck0); aF[mi][1] = LDA(h, 4 + mi, ck1); }
      STAGE(B, brow0, T + 2, h, 1, 0);
      PH_PRE();
      #pragma unroll
      for (int mi = 0; mi < 4; ++mi)
        #pragma unroll
        for (int ni = 0; ni < 2; ++ni)
          #pragma unroll
          for (int kk = 0; kk < 2; ++kk)
            acc[4 + mi][ni] = mfma_bf16(aF[mi][kk], bF[ni][kk], acc[4 + mi][ni]);
      PH_POST();
      // ---- g4: no reads (A-halves of buf h now dead); stage (buf h).B1 <- tile T+2
      STAGE(B, brow0, T + 2, h, 1, 1);
      PH_PRE();
      #pragma unroll
      for (int mi = 0; mi < 4; ++mi)
        #pragma unroll
        for (int ni = 2; ni < 4; ++ni)
          #pragma unroll
          for (int kk = 0; kk < 2; ++kk)
            acc[4 + mi][ni] = mfma_bf16(aF[mi][kk], bF[ni][kk], acc[4 + mi][ni]);
      if (last) { PH_POST_VM0(); } else { PH_POST_VM4(); }
    }
  }

  asm volatile("s_nop 7\n\ts_nop 7\n\ts_nop 7" ::);  // MFMA->VALU hazard drain
  const int rb = arow0 + wr * 128 + l4 * 4;
  const int cb = bn * 256 + wc * 64 + l15;
  #pragma unroll
  for (int ni = 0; ni < 4; ++ni) {
    const int col = cb + ni * 16;
    const float bv = bias[col];
    #pragma unroll
    for (int mi = 0; mi < 8; ++mi)
      #pragma unroll
      for (int jj = 0; jj < 4; ++jj)
        C[(size_t)(rb + mi * 16 + jj) * N + col] = f2bf(acc[mi][ni][jj] + bv);
  }
}

// ---------------- 128x128 MFMA GEMM (m97-style), used for logits GEMM ----------------
template <typename OutT>
__global__ __launch_bounds__(256, 2) void gemm_bt(
    const uint16_t* __restrict__ A, const uint16_t* __restrict__ B,
    const float* __restrict__ bias, OutT* __restrict__ C, int N, int K) {
  __shared__ __align__(16) uint16_t As[128 * 64];
  __shared__ __align__(16) uint16_t Bs[128 * 64];
  const int tid = threadIdx.x;
  const int w = tid >> 6, lane = tid & 63;
  const int wr = w >> 1, wc = w & 1;
  const int tm = blockIdx.x, tn = blockIdx.y;

  f32x4 acc[4][4] = {};

  const int lrow = lane >> 3;
  const int lk = (lane & 7) * 8;
  const size_t a_row0 = (size_t)tm * 128;
  const size_t b_row0 = (size_t)tn * 128;

  for (int k0 = 0; k0 < K; k0 += 64) {
    #pragma unroll
    for (int j = 0; j < 4; ++j) {
      const int c = w * 4 + j;
      const int row = c * 8 + lrow;
      async_load16(A + (a_row0 + row) * K + k0 + lk, (void*)(As + c * 512));
      async_load16(B + (b_row0 + row) * K + k0 + lk, (void*)(Bs + c * 512));
    }
    __syncthreads();
    #pragma unroll
    for (int kk = 0; kk < 2; ++kk) {
      const int krow = kk * 32 + (lane >> 4) * 8;
      s16x8 af[4], bfr[4];
      #pragma unroll
      for (int mi = 0; mi < 4; ++mi)
        af[mi] = *(const s16x8*)&As[(wr * 64 + mi * 16 + (lane & 15)) * 64 + krow];
      #pragma unroll
      for (int ni = 0; ni < 4; ++ni)
        bfr[ni] = *(const s16x8*)&Bs[(wc * 64 + ni * 16 + (lane & 15)) * 64 + krow];
      #pragma unroll
      for (int mi = 0; mi < 4; ++mi)
        #pragma unroll
        for (int ni = 0; ni < 4; ++ni)
          acc[mi][ni] = mfma_bf16(af[mi], bfr[ni], acc[mi][ni]);
    }
    __syncthreads();
  }
  asm volatile("s_nop 7\n\ts_nop 7\n\ts_nop 7" ::);

  const int rbase = wr * 64 + (lane >> 4) * 4;
  const int cbase = wc * 64 + (lane & 15);
  #pragma unroll
  for (int ni = 0; ni < 4; ++ni) {
    const int col = tn * 128 + cbase + ni * 16;
    const float bv = bias[col];
    #pragma unroll
    for (int mi = 0; mi < 4; ++mi) {
      #pragma unroll
      for (int jj = 0; jj < 4; ++jj) {
        const int row = tm * 128 + rbase + mi * 16 + jj;
        float v = acc[mi][ni][jj] + bv;
        if constexpr (sizeof(OutT) == 2) C[(size_t)row * N + col] = (OutT)f2bf(v);
        else                             C[(size_t)row * N + col] = v;
      }
    }
  }
}

// ---------------- fused softmax + partial accumulate ----------------
__global__ __launch_bounds__(256) void softmax_accum(
    const float* __restrict__ logits,   // R x 384 (0..255 = a1 logits, 256..263 = a2)
    const uint16_t* __restrict__ xe,    // R x 2048 bf16
    float* __restrict__ t1,             // 32 x 256
    float* __restrict__ sacc) {         // 32 x 32
  const int tid = threadIdx.x;
  const int r0 = blockIdx.x * 32;
  const int b = r0 >> 9;
  __shared__ float p1s[256];
  __shared__ float a2s[8];
  float t1_local = 0.0f, s_local = 0.0f;

  for (int rr = 0; rr < 32; ++rr) {
    const int r = r0 + rr;
    const float* lrow = logits + (size_t)r * NCAT;
    float lg = lrow[tid];
    float mx = lg;
    #pragma unroll
    for (int m = 16; m; m >>= 1) mx = fmaxf(mx, __shfl_xor(mx, m));
    float e = __expf(lg - mx);
    float sm = e;
    #pragma unroll
    for (int m = 16; m; m >>= 1) sm += __shfl_xor(sm, m);
    p1s[tid] = e / sm;
    if (tid < 8) {
      float l2 = lrow[256 + tid];
      float m2 = l2;
      #pragma unroll
      for (int m = 4; m; m >>= 1) m2 = fmaxf(m2, __shfl_xor(m2, m));
      float e2 = __expf(l2 - m2);
      float s2 = e2;
      #pragma unroll
      for (int m = 4; m; m >>= 1) s2 += __shfl_xor(s2, m);
      a2s[tid] = e2 / s2;
    }
    __syncthreads();
    const uint16_t* xr = xe + (size_t)r * E_DIM;
    float a = 0.0f;
    #pragma unroll
    for (int g = 0; g < 8; ++g) a += a2s[g] * bf2f(xr[g * 256 + tid]);
    t1_local += a;
    if (tid < 32) {
      float sa = 0.0f;
      #pragma unroll
      for (int g = 0; g < 8; ++g) sa += a2s[g] * p1s[g * 32 + tid];
      s_local += sa;
    }
    __syncthreads();
  }
  atomicAdd(&t1[b * 256 + tid], t1_local);
  if (tid < 32) atomicAdd(&sacc[b * 32 + tid], s_local);
}

// ---------------- finalize ----------------
__global__ __launch_bounds__(256) void finalize(const float* __restrict__ t1,
                                                const float* __restrict__ sacc,
                                                const float* __restrict__ centroid,
                                                float* __restrict__ out) {
  const int b = blockIdx.x, tid = threadIdx.x;
  float cs = 0.0f;
  #pragma unroll
  for (int k = 0; k < 32; ++k) cs += sacc[b * 32 + k] * centroid[k * 256 + tid];
  float v = (t1[b * 256 + tid] - cs) * (1.0f / (float)M_SEQ);
  float ss = v * v;
  #pragma unroll
  for (int m = 32; m; m >>= 1) ss += __shfl_xor(ss, m);
  __shared__ float wsum[4];
  if ((tid & 63) == 0) wsum[tid >> 6] = ss;
  __syncthreads();
  float tot = wsum[0] + wsum[1] + wsum[2] + wsum[3];
  out[b * 256 + tid] = v / fmaxf(sqrtf(tot), 1e-12f);
}

extern "C" void kernel_launch(void* const* d_in, const int* in_sizes, int n_in,
                              void* d_out, int out_size, void* d_ws, size_t ws_size,
                              hipStream_t stream) {
  const float* x        = (const float*)d_in[0];
  // d_in[1] = mask (unused by reference math)
  const float* We       = (const float*)d_in[2];
  const float* be       = (const float*)d_in[3];
  const float* W1       = (const float*)d_in[4];
  const float* b1       = (const float*)d_in[5];
  const float* W2       = (const float*)d_in[6];
  const float* b2       = (const float*)d_in[7];
  const float* centroid = (const float*)d_in[8];
  float* out = (float*)d_out;

  char* ws = (char*)d_ws;
  // workspace layout (bytes), total ~101.5 MB; logits aliases xn (stream-ordered safe)
  uint16_t* xe     = (uint16_t*)(ws + 0);          //  64 MB  R x 2048 bf16
  uint16_t* xn     = (uint16_t*)(ws + 67108864);   //  32 MB  R x 1024 bf16
  float*    logits = (float*)  (ws + 67108864);    //  24 MB  R x 384 f32 (aliases xn)
  uint16_t* webf   = (uint16_t*)(ws + 100663296);  //   4 MB  2048 x 1024 bf16
  uint16_t* wcat   = (uint16_t*)(ws + 104857600);  // 1.5 MB  384 x 2048 bf16
  float*    bcat   = (float*)  (ws + 106430464);   //  1.5 KB 384 f32
  float*    t1     = (float*)  (ws + 106432000);   //  32 KB  32 x 256
  float*    sacc   = (float*)  (ws + 106464768);   //   4 KB  32 x 32

  // prep
  zero_buf  <<<dim3(36),   256, 0, stream>>>(t1, 8192 + 1024);
  cvt_bf16  <<<dim3(8192), 256, 0, stream>>>(We, webf, E_DIM * D_IN);
  build_wcat<<<dim3(3072), 256, 0, stream>>>(W1, W2, wcat);
  build_bcat<<<dim3(2),    256, 0, stream>>>(b1, b2, bcat);

  // pipeline
  normalize_rows<<<dim3(R_TOT), 256, 0, stream>>>(x, xn);
  gemm256<D_IN><<<dim3(R_TOT / 256, E_DIM / 256), 512, 0, stream>>>(
      xn, webf, be, xe, E_DIM);
  gemm_bt<float><<<dim3(R_TOT / 128, NCAT / 128), 256, 0, stream>>>(
      xe, wcat, bcat, logits, NCAT, E_DIM);
  softmax_accum<<<dim3(R_TOT / 32), 256, 0, stream>>>(logits, xe, t1, sacc);
  finalize<<<dim3(B_BATCH), 256, 0, stream>>>(t1, sacc, centroid, out);
}

// Round 7
// 300.051 us; speedup vs baseline: 1.0218x; 1.0030x over previous
//
#include <hip/hip_runtime.h>
#include <hip/hip_bf16.h>
#include <stdint.h>

// Problem constants
#define B_BATCH 32
#define M_SEQ   512
#define R_TOT   16384      // B*M
#define D_IN    1024
#define E_DIM   2048       // lmd*d
#define NCAT    384        // 256 (G*NC) + 8 (G) padded to 3*128
#define NVALID  264

typedef float  f32x4 __attribute__((ext_vector_type(4)));
typedef short  s16x8 __attribute__((ext_vector_type(8)));

__device__ __forceinline__ uint16_t f2bf(float f) {
  uint32_t u = __builtin_bit_cast(uint32_t, f);
  uint32_t r = (u + 0x7fffu + ((u >> 16) & 1u)) >> 16;
  return (uint16_t)r;
}
__device__ __forceinline__ float bf2f(uint16_t u) {
  return __builtin_bit_cast(float, (uint32_t)u << 16);
}

__device__ __forceinline__ f32x4 mfma_bf16(s16x8 a, s16x8 b, f32x4 c) {
  asm("v_mfma_f32_16x16x32_bf16 %0, %1, %2, %0" : "+v"(c) : "v"(a), "v"(b));
  return c;
}

typedef __attribute__((address_space(3))) void lds_void_t;
typedef const __attribute__((address_space(1))) void gbl_void_t;
__device__ __forceinline__ void async_load16(const void* g, void* l) {
  __builtin_amdgcn_global_load_lds((gbl_void_t*)g, (lds_void_t*)l, 16, 0, 0);
}

#define FENCE() __builtin_amdgcn_sched_barrier(0)
#define PH_PRE() do { FENCE(); __builtin_amdgcn_s_barrier(); FENCE(); \
                      asm volatile("s_waitcnt lgkmcnt(0)" ::: "memory"); FENCE(); \
                      __builtin_amdgcn_s_setprio(1); } while (0)
#define PH_POST() do { __builtin_amdgcn_s_setprio(0); FENCE(); \
                       __builtin_amdgcn_s_barrier(); FENCE(); } while (0)
#define PH_POST_VM4() do { __builtin_amdgcn_s_setprio(0); FENCE(); \
                       asm volatile("s_waitcnt vmcnt(4)" ::: "memory"); FENCE(); \
                       __builtin_amdgcn_s_barrier(); FENCE(); } while (0)
#define PH_POST_VM0() do { __builtin_amdgcn_s_setprio(0); FENCE(); \
                       asm volatile("s_waitcnt vmcnt(0)" ::: "memory"); FENCE(); \
                       __builtin_amdgcn_s_barrier(); FENCE(); } while (0)

// ---------------- prep kernels ----------------
__global__ void zero_buf(float* __restrict__ p, int n) {
  int i = blockIdx.x * blockDim.x + threadIdx.x;
  if (i < n) p[i] = 0.0f;
}

__global__ void cvt_bf16(const float* __restrict__ src, uint16_t* __restrict__ dst, int n) {
  int i = blockIdx.x * blockDim.x + threadIdx.x;
  if (i < n) dst[i] = f2bf(src[i]);
}

__global__ void build_wcat(const float* __restrict__ W1, const float* __restrict__ W2,
                           uint16_t* __restrict__ wcat) {
  int i = blockIdx.x * blockDim.x + threadIdx.x;
  if (i >= NCAT * E_DIM) return;
  int row = i >> 11, col = i & (E_DIM - 1);
  float v = 0.0f;
  if (row < 256) v = W1[i];
  else if (row < NVALID) v = W2[(row - 256) * E_DIM + col];
  wcat[i] = f2bf(v);
}

__global__ void build_bcat(const float* __restrict__ b1, const float* __restrict__ b2,
                           float* __restrict__ bcat) {
  int i = blockIdx.x * blockDim.x + threadIdx.x;
  if (i >= NCAT) return;
  float v = 0.0f;
  if (i < 256) v = b1[i];
  else if (i < NVALID) v = b2[i - 256];
  bcat[i] = v;
}

// ---------------- row L2-normalize -> bf16 ----------------
__global__ __launch_bounds__(256) void normalize_rows(const float* __restrict__ x,
                                                      uint16_t* __restrict__ xn) {
  const int r = blockIdx.x, tid = threadIdx.x;
  const float4* xr = (const float4*)(x + (size_t)r * D_IN);
  float4 v = xr[tid];
  float ss = v.x * v.x + v.y * v.y + v.z * v.z + v.w * v.w;
  #pragma unroll
  for (int m = 32; m; m >>= 1) ss += __shfl_xor(ss, m);
  __shared__ float wsum[4];
  if ((tid & 63) == 0) wsum[tid >> 6] = ss;
  __syncthreads();
  float tot = wsum[0] + wsum[1] + wsum[2] + wsum[3];
  float scale = 1.0f / fmaxf(sqrtf(tot), 1e-12f);
  uint16_t* o = xn + (size_t)r * D_IN + tid * 4;
  o[0] = f2bf(v.x * scale); o[1] = f2bf(v.y * scale);
  o[2] = f2bf(v.z * scale); o[3] = f2bf(v.w * scale);
}

// ---------------- 256x256 8-phase MFMA GEMM (T2+T3+T4+T5) ----------------
// C[M,N] = A[M,K] @ B[N,K]^T + bias, bf16 out. 512 thr (8 waves 2Mx4N), BK=64,
// LDS [2 buf][A/B][2 half][128x64] = 128 KB, XOR-chunk swizzle via pre-swizzled
// global source + swizzled ds_read. Counted vmcnt(4) per group. kk-outer MFMA
// order (dep distance 8). Epilogue staged through LDS (swizzled) for coalesced
// full-line bf16 stores.
template <int KDIM>
__global__ __launch_bounds__(512, 2) void gemm256(
    const uint16_t* __restrict__ A, const uint16_t* __restrict__ B,
    const float* __restrict__ bias, uint16_t* __restrict__ C, int N) {
  __shared__ uint16_t lds[65536];
  constexpr int NT = KDIM / 64;
  const int tid = threadIdx.x;
  const int w = tid >> 6, lane = tid & 63;
  const int wr = w >> 2, wc = w & 3;
  const int bm = blockIdx.x, bn = blockIdx.y;

  const int srow = tid >> 3;
  const int scol = (((tid & 7) ^ (srow & 7)) << 3);
  const int l15 = lane & 15, l4 = lane >> 4, lx = lane & 7;
  const int ck0 = ((l4) ^ lx) << 4;
  const int ck1 = ((4 + l4) ^ lx) << 4;

  const int arow0 = bm * 256, brow0 = bn * 256;

  auto STAGE = [&](const uint16_t* __restrict__ M, int grow0, int tile,
                   int bufi, int mat, int half) {
    if (tile >= NT) return;
    const uint16_t* src = M + (size_t)(grow0 + half * 128 + srow) * KDIM + tile * 64 + scol;
    uint16_t* dst = lds + ((bufi * 2 + mat) * 2 + half) * 8192 + w * 512;
    async_load16(src, dst);
    async_load16(src + (size_t)64 * KDIM, dst + 4096);
  };
  auto LDA = [&](int bufi, int mi, int ckb) -> s16x8 {
    return *(const s16x8*)((const char*)(lds + ((bufi * 2 + 0) * 2 + wr) * 8192)
                           + (mi * 16 + l15) * 128 + ckb);
  };
  auto LDB = [&](int bufi, int ni, int ckb) -> s16x8 {
    return *(const s16x8*)((const char*)(lds + ((bufi * 2 + 1) * 2 + (wc >> 1)) * 8192)
                           + ((wc & 1) * 64 + ni * 16 + l15) * 128 + ckb);
  };

  f32x4 acc[8][4] = {};
  s16x8 aF[4][2], bF[4][2];

  // prologue: tile0 fully, tile1 B-halves
  STAGE(A, arow0, 0, 0, 0, 0); STAGE(A, arow0, 0, 0, 0, 1);
  STAGE(B, brow0, 0, 0, 1, 0); STAGE(B, brow0, 0, 0, 1, 1);
  STAGE(B, brow0, 1, 1, 1, 0); STAGE(B, brow0, 1, 1, 1, 1);
  asm volatile("s_waitcnt vmcnt(4)" ::: "memory");
  __builtin_amdgcn_s_barrier(); FENCE();

  for (int i = 0; i < NT / 2; ++i) {
    const bool last = (i == NT / 2 - 1);
    #pragma unroll
    for (int h = 0; h < 2; ++h) {
      const int T = 2 * i + h;
      // ---- g1: read a0-3,b0-1; stage (buf h^1).A0 <- tile T+1
      #pragma unroll
      for (int mi = 0; mi < 4; ++mi) { aF[mi][0] = LDA(h, mi, ck0); aF[mi][1] = LDA(h, mi, ck1); }
      #pragma unroll
      for (int ni = 0; ni < 2; ++ni) { bF[ni][0] = LDB(h, ni, ck0); bF[ni][1] = LDB(h, ni, ck1); }
      STAGE(A, arow0, T + 1, h ^ 1, 0, 0);
      PH_PRE();
      #pragma unroll
      for (int kk = 0; kk < 2; ++kk)
        #pragma unroll
        for (int mi = 0; mi < 4; ++mi)
          #pragma unroll
          for (int ni = 0; ni < 2; ++ni)
            acc[mi][ni] = mfma_bf16(aF[mi][kk], bF[ni][kk], acc[mi][ni]);
      PH_POST();
      // ---- g2: read b2-3; stage (buf h^1).A1 <- tile T+1
      #pragma unroll
      for (int ni = 2; ni < 4; ++ni) { bF[ni][0] = LDB(h, ni, ck0); bF[ni][1] = LDB(h, ni, ck1); }
      STAGE(A, arow0, T + 1, h ^ 1, 0, 1);
      PH_PRE();
      #pragma unroll
      for (int kk = 0; kk < 2; ++kk)
        #pragma unroll
        for (int mi = 0; mi < 4; ++mi)
          #pragma unroll
          for (int ni = 2; ni < 4; ++ni)
            acc[mi][ni] = mfma_bf16(aF[mi][kk], bF[ni][kk], acc[mi][ni]);
      PH_POST();
      // ---- g3: read a4-7; stage (buf h).B0 <- tile T+2
      #pragma unroll
      for (int mi = 0; mi < 4; ++mi) { aF[mi][0] = LDA(h, 4 + mi, ck0); aF[mi][1] = LDA(h, 4 + mi, ck1); }
      STAGE(B, brow0, T + 2, h, 1, 0);
      PH_PRE();
      #pragma unroll
      for (int kk = 0; kk < 2; ++kk)
        #pragma unroll
        for (int mi = 0; mi < 4; ++mi)
          #pragma unroll
          for (int ni = 0; ni < 2; ++ni)
            acc[4 + mi][ni] = mfma_bf16(aF[mi][kk], bF[ni][kk], acc[4 + mi][ni]);
      PH_POST();
      // ---- g4: no reads; stage (buf h).B1 <- tile T+2
      STAGE(B, brow0, T + 2, h, 1, 1);
      PH_PRE();
      #pragma unroll
      for (int kk = 0; kk < 2; ++kk)
        #pragma unroll
        for (int mi = 0; mi < 4; ++mi)
          #pragma unroll
          for (int ni = 2; ni < 4; ++ni)
            acc[4 + mi][ni] = mfma_bf16(aF[mi][kk], bF[ni][kk], acc[4 + mi][ni]);
      if (last) { PH_POST_VM0(); } else { PH_POST_VM4(); }
    }
  }

  asm volatile("s_nop 7\n\ts_nop 7\n\ts_nop 7" ::);  // MFMA->VALU hazard drain

  // ---- epilogue: stage C-tile in LDS (16B-granule XOR swizzle), then
  // fully-coalesced stores (each thread: 256 contiguous bytes, full 64B lines)
  const int lr0 = wr * 128 + l4 * 4;
  const int lc0 = wc * 64 + l15;
  #pragma unroll
  for (int ni = 0; ni < 4; ++ni) {
    const int col = lc0 + ni * 16;
    const float bv = bias[bn * 256 + col];
    const int c16 = col >> 3, c7 = col & 7;
    #pragma unroll
    for (int mi = 0; mi < 8; ++mi) {
      #pragma unroll
      for (int jj = 0; jj < 4; ++jj) {
        const int row = lr0 + mi * 16 + jj;
        lds[row * 256 + ((c16 ^ (row & 31)) << 3) + c7] = f2bf(acc[mi][ni][jj] + bv);
      }
    }
  }
  __syncthreads();
  {
    const int row = tid >> 1, ch = tid & 1;
    const int r31 = row & 31;
    uint16_t* dst = C + (size_t)(arow0 + row) * N + bn * 256 + ch * 128;
    #pragma unroll
    for (int q = 0; q < 8; ++q) {
      const int c16a = ch * 16 + 2 * q;
      s16x8 v0 = *(const s16x8*)&lds[row * 256 + ((c16a ^ r31) << 3)];
      s16x8 v1 = *(const s16x8*)&lds[row * 256 + (((c16a + 1) ^ r31) << 3)];
      *(s16x8*)(dst + q * 16) = v0;
      *(s16x8*)(dst + q * 16 + 8) = v1;
    }
  }
}

// ---------------- 128x128 MFMA GEMM (m97-style), used for logits GEMM ----------------
template <typename OutT>
__global__ __launch_bounds__(256, 2) void gemm_bt(
    const uint16_t* __restrict__ A, const uint16_t* __restrict__ B,
    const float* __restrict__ bias, OutT* __restrict__ C, int N, int K) {
  __shared__ __align__(16) uint16_t As[128 * 64];
  __shared__ __align__(16) uint16_t Bs[128 * 64];
  const int tid = threadIdx.x;
  const int w = tid >> 6, lane = tid & 63;
  const int wr = w >> 1, wc = w & 1;
  const int tm = blockIdx.x, tn = blockIdx.y;

  f32x4 acc[4][4] = {};

  const int lrow = lane >> 3;
  const int lk = (lane & 7) * 8;
  const size_t a_row0 = (size_t)tm * 128;
  const size_t b_row0 = (size_t)tn * 128;

  for (int k0 = 0; k0 < K; k0 += 64) {
    #pragma unroll
    for (int j = 0; j < 4; ++j) {
      const int c = w * 4 + j;
      const int row = c * 8 + lrow;
      async_load16(A + (a_row0 + row) * K + k0 + lk, (void*)(As + c * 512));
      async_load16(B + (b_row0 + row) * K + k0 + lk, (void*)(Bs + c * 512));
    }
    __syncthreads();
    #pragma unroll
    for (int kk = 0; kk < 2; ++kk) {
      const int krow = kk * 32 + (lane >> 4) * 8;
      s16x8 af[4], bfr[4];
      #pragma unroll
      for (int mi = 0; mi < 4; ++mi)
        af[mi] = *(const s16x8*)&As[(wr * 64 + mi * 16 + (lane & 15)) * 64 + krow];
      #pragma unroll
      for (int ni = 0; ni < 4; ++ni)
        bfr[ni] = *(const s16x8*)&Bs[(wc * 64 + ni * 16 + (lane & 15)) * 64 + krow];
      #pragma unroll
      for (int mi = 0; mi < 4; ++mi)
        #pragma unroll
        for (int ni = 0; ni < 4; ++ni)
          acc[mi][ni] = mfma_bf16(af[mi], bfr[ni], acc[mi][ni]);
    }
    __syncthreads();
  }
  asm volatile("s_nop 7\n\ts_nop 7\n\ts_nop 7" ::);

  const int rbase = wr * 64 + (lane >> 4) * 4;
  const int cbase = wc * 64 + (lane & 15);
  #pragma unroll
  for (int ni = 0; ni < 4; ++ni) {
    const int col = tn * 128 + cbase + ni * 16;
    const float bv = bias[col];
    #pragma unroll
    for (int mi = 0; mi < 4; ++mi) {
      #pragma unroll
      for (int jj = 0; jj < 4; ++jj) {
        const int row = tm * 128 + rbase + mi * 16 + jj;
        float v = acc[mi][ni][jj] + bv;
        if constexpr (sizeof(OutT) == 2) C[(size_t)row * N + col] = (OutT)f2bf(v);
        else                             C[(size_t)row * N + col] = v;
      }
    }
  }
}

// ---------------- fused softmax + partial accumulate ----------------
__global__ __launch_bounds__(256) void softmax_accum(
    const float* __restrict__ logits,   // R x 384 (0..255 = a1 logits, 256..263 = a2)
    const uint16_t* __restrict__ xe,    // R x 2048 bf16
    float* __restrict__ t1,             // 32 x 256
    float* __restrict__ sacc) {         // 32 x 32
  const int tid = threadIdx.x;
  const int r0 = blockIdx.x * 32;
  const int b = r0 >> 9;
  __shared__ float p1s[256];
  __shared__ float a2s[8];
  float t1_local = 0.0f, s_local = 0.0f;

  for (int rr = 0; rr < 32; ++rr) {
    const int r = r0 + rr;
    const float* lrow = logits + (size_t)r * NCAT;
    float lg = lrow[tid];
    float mx = lg;
    #pragma unroll
    for (int m = 16; m; m >>= 1) mx = fmaxf(mx, __shfl_xor(mx, m));
    float e = __expf(lg - mx);
    float sm = e;
    #pragma unroll
    for (int m = 16; m; m >>= 1) sm += __shfl_xor(sm, m);
    p1s[tid] = e / sm;
    if (tid < 8) {
      float l2 = lrow[256 + tid];
      float m2 = l2;
      #pragma unroll
      for (int m = 4; m; m >>= 1) m2 = fmaxf(m2, __shfl_xor(m2, m));
      float e2 = __expf(l2 - m2);
      float s2 = e2;
      #pragma unroll
      for (int m = 4; m; m >>= 1) s2 += __shfl_xor(s2, m);
      a2s[tid] = e2 / s2;
    }
    __syncthreads();
    const uint16_t* xr = xe + (size_t)r * E_DIM;
    float a = 0.0f;
    #pragma unroll
    for (int g = 0; g < 8; ++g) a += a2s[g] * bf2f(xr[g * 256 + tid]);
    t1_local += a;
    if (tid < 32) {
      float sa = 0.0f;
      #pragma unroll
      for (int g = 0; g < 8; ++g) sa += a2s[g] * p1s[g * 32 + tid];
      s_local += sa;
    }
    __syncthreads();
  }
  atomicAdd(&t1[b * 256 + tid], t1_local);
  if (tid < 32) atomicAdd(&sacc[b * 32 + tid], s_local);
}

// ---------------- finalize ----------------
__global__ __launch_bounds__(256) void finalize(const float* __restrict__ t1,
                                                const float* __restrict__ sacc,
                                                const float* __restrict__ centroid,
                                                float* __restrict__ out) {
  const int b = blockIdx.x, tid = threadIdx.x;
  float cs = 0.0f;
  #pragma unroll
  for (int k = 0; k < 32; ++k) cs += sacc[b * 32 + k] * centroid[k * 256 + tid];
  float v = (t1[b * 256 + tid] - cs) * (1.0f / (float)M_SEQ);
  float ss = v * v;
  #pragma unroll
  for (int m = 32; m; m >>= 1) ss += __shfl_xor(ss, m);
  __shared__ float wsum[4];
  if ((tid & 63) == 0) wsum[tid >> 6] = ss;
  __syncthreads();
  float tot = wsum[0] + wsum[1] + wsum[2] + wsum[3];
  out[b * 256 + tid] = v / fmaxf(sqrtf(tot), 1e-12f);
}

extern "C" void kernel_launch(void* const* d_in, const int* in_sizes, int n_in,
                              void* d_out, int out_size, void* d_ws, size_t ws_size,
                              hipStream_t stream) {
  const float* x        = (const float*)d_in[0];
  // d_in[1] = mask (unused by reference math)
  const float* We       = (const float*)d_in[2];
  const float* be       = (const float*)d_in[3];
  const float* W1       = (const float*)d_in[4];
  const float* b1       = (const float*)d_in[5];
  const float* W2       = (const float*)d_in[6];
  const float* b2       = (const float*)d_in[7];
  const float* centroid = (const float*)d_in[8];
  float* out = (float*)d_out;

  char* ws = (char*)d_ws;
  // workspace layout (bytes), total ~101.5 MB; logits aliases xn (stream-ordered safe)
  uint16_t* xe     = (uint16_t*)(ws + 0);          //  64 MB  R x 2048 bf16
  uint16_t* xn     = (uint16_t*)(ws + 67108864);   //  32 MB  R x 1024 bf16
  float*    logits = (float*)  (ws + 67108864);    //  24 MB  R x 384 f32 (aliases xn)
  uint16_t* webf   = (uint16_t*)(ws + 100663296);  //   4 MB  2048 x 1024 bf16
  uint16_t* wcat   = (uint16_t*)(ws + 104857600);  // 1.5 MB  384 x 2048 bf16
  float*    bcat   = (float*)  (ws + 106430464);   //  1.5 KB 384 f32
  float*    t1     = (float*)  (ws + 106432000);   //  32 KB  32 x 256
  float*    sacc   = (float*)  (ws + 106464768);   //   4 KB  32 x 32

  // prep
  zero_buf  <<<dim3(36),   256, 0, stream>>>(t1, 8192 + 1024);
  cvt_bf16  <<<dim3(8192), 256, 0, stream>>>(We, webf, E_DIM * D_IN);
  build_wcat<<<dim3(3072), 256, 0, stream>>>(W1, W2, wcat);
  build_bcat<<<dim3(2),    256, 0, stream>>>(b1, b2, bcat);

  // pipeline
  normalize_rows<<<dim3(R_TOT), 256, 0, stream>>>(x, xn);
  gemm256<D_IN><<<dim3(R_TOT / 256, E_DIM / 256), 512, 0, stream>>>(
      xn, webf, be, xe, E_DIM);
  gemm_bt<float><<<dim3(R_TOT / 128, NCAT / 128), 256, 0, stream>>>(
      xe, wcat, bcat, logits, NCAT, E_DIM);
  softmax_accum<<<dim3(R_TOT / 32), 256, 0, stream>>>(logits, xe, t1, sacc);
  finalize<<<dim3(B_BATCH), 256, 0, stream>>>(t1, sacc, centroid, out);
}